// Round 11
// baseline (7166.125 us; speedup 1.0000x reference)
//
#include <hip/hip_runtime.h>

#define T_STEPS 2048
#define BATCH   256
#define HID     512
#define NG      16   // gate-slice blocks per batch group (h-cols 512/NG = 32 each)
#define NB      16   // batch groups (rows 256/NB = 16 each)
#define RING    6    // h ring slots (sentinel dataflow protocol)
#define SENT    0x3C3C3C3C  // fp16 pair (1.0586,1.0586) — unreachable: |h|<=1.0

typedef _Float16 half8 __attribute__((ext_vector_type(8)));
typedef float f32x4 __attribute__((ext_vector_type(4)));
typedef int int4v __attribute__((ext_vector_type(4)));

__device__ __forceinline__ float sigmoid_f(float v) {
    return 1.f / (1.f + __expf(-v));
}
__device__ __forceinline__ float tanh_f(float v) {
    float a = fabsf(v);
    float e = __expf(2.f * a);
    float r = 1.f - 2.f / (e + 1.f);
    return copysignf(r, v);
}
__device__ __forceinline__ bool gvalid(int4v p) {
    return p[0] != (int)SENT && p[1] != (int)SENT &&
           p[2] != (int)SENT && p[3] != (int)SENT;
}

// early-probe issue: 4 line-granule loads into persistent probe regs q0..q3
#define PROBE(addr)                                                           \
    asm volatile(                                                             \
        "global_load_dwordx4 %0, %4, off sc0 sc1\n\t"                         \
        "global_load_dwordx4 %1, %4, off offset:64 sc0 sc1\n\t"               \
        "global_load_dwordx4 %2, %4, off offset:128 sc0 sc1\n\t"              \
        "global_load_dwordx4 %3, %4, off offset:192 sc0 sc1"                  \
        : "=&v"(q0), "=&v"(q1), "=&v"(q2), "=&v"(q3)                          \
        : "v"(addr) : "memory")

// loop-top / post-loop: drain ALL outstanding VM ops (probe + older stores)
// with probe regs bound — no in-flight load may outlive its register binding
// (round-8 lesson).
#define WAITQ()                                                               \
    asm volatile("s_waitcnt vmcnt(0)"                                         \
        : "+v"(q0), "+v"(q1), "+v"(q2), "+v"(q3) :: "memory")

// grid = 256 blocks (g = blockIdx&15 batch group, j = blockIdx>>4 gate slice)
// block = 256 threads = 4 waves, K-split (wave w owns k in [128w,128w+128)).
// Sentinel-dataflow sync (round-7 proven): 6-slot h ring; producers store h
// (sc0|sc1, MALL-coherent); consumers poll their own A-fragment granules until
// != SENT — the poll IS the load. Consumed slot reset to SENT after the
// mid-step barrier (4-step visibility slack before re-poll). Values in a slot
// are immutable between write and reset, so re-reads are always consistent.
// NEW (r9/r10): the FIRST sample of step t+1's slot is issued during step t
// (after barrier+reset, before epilogue) so its flight overlaps epilogue +
// h-store; at next loop-top it usually lands valid -> detect leg ~free.
__global__ __launch_bounds__(256, 1) void lstm_persistent(
    const float* __restrict__ x,     // (T,B)
    const float* __restrict__ Wih,   // (4H,1)
    const float* __restrict__ Whh,   // (4H,H)
    const float* __restrict__ bih,   // (4H)
    const float* __restrict__ bhh,   // (4H)
    const float* __restrict__ Wlin,  // (1,H)
    _Float16* __restrict__ hbuf,     // [RING][B][H] fp16
    float* __restrict__ partial)     // [NG][B]
{
    const int tid  = threadIdx.x;
    const int g    = blockIdx.x & 15;   // batch group
    const int j    = blockIdx.x >> 4;   // gate slice
    const int wave = tid >> 6;          // k-slice owner
    const int lane = tid & 63;
    const int quad = lane >> 4;
    const int ln16 = lane & 15;

    // pad 36: write bank = (16q + 4r + col) % 32 -> exact 2-way (free);
    // measured (r9): conflicts 2.01e8 -> 6.7e7 vs pad-34.
    __shared__ float lds_part[2][4][4][16][36];

    // ---- stationary weights: fp16 MFMA B-fragments in registers ----
    half8 bf[4][2][4];
    #pragma unroll
    for (int gt = 0; gt < 4; ++gt) {
        #pragma unroll
        for (int ch = 0; ch < 2; ++ch) {
            const float* wr = Whh + (size_t)(gt * 512 + j * 32 + ch * 16 + ln16) * HID;
            #pragma unroll
            for (int ksl = 0; ksl < 4; ++ksl) {
                int k0 = (wave * 4 + ksl) * 32 + quad * 8;
                half8 v;
                #pragma unroll
                for (int e = 0; e < 8; ++e) v[e] = (_Float16)wr[k0 + e];
                bf[gt][ch][ksl] = v;
            }
        }
    }

    const int row_e = tid >> 4;          // epilogue row 0..15
    const int cp    = (tid & 15) * 2;    // epilogue col pair 0,2,..,30

    float wxA[4], wxB[4], bsA[4], bsB[4];
    #pragma unroll
    for (int gt = 0; gt < 4; ++gt) {
        int r0 = gt * 512 + j * 32 + cp;
        wxA[gt] = Wih[r0];
        wxB[gt] = Wih[r0 + 1];
        bsA[gt] = bih[r0] + bhh[r0];
        bsB[gt] = bih[r0 + 1] + bhh[r0 + 1];
    }

    float c0 = 0.f, c1 = 0.f;
    float hl0 = 0.f, hl1 = 0.f;
    bool  dead = false;

    float x_cur = x[(size_t)g * 16 + row_e];   // x for t=0

    const int4v sent4 = {(int)SENT, (int)SENT, (int)SENT, (int)SENT};
    int s_in = 0, s_out = 1, s_rst = 5;

    // per-lane A-fragment base (slot 0); slot stride = 256 KB
    const unsigned long long lane_base = (unsigned long long)(
        (const char*)hbuf + ((size_t)(g * 16 + ln16) * HID) * 2
        + wave * 256 + quad * 16);
    const unsigned long long slot_stride = (unsigned long long)BATCH * HID * 2;

    int4v q0, q1, q2, q3;                // persistent probe regs
    PROBE(lane_base);                    // first sample for t=0 (slot 0 = zeros)

    for (int t = 0; t < T_STEPS; ++t) {
        const unsigned long long haddr = lane_base + (unsigned long long)s_in * slot_stride;

        // ---- loop-top: land the early probe (+ retire older stores) ----
        WAITQ();
        int4v h0 = q0, h1 = q1, h2 = q2, h3 = q3;
        bool allv = gvalid(h0) && gvalid(h1) && gvalid(h2) && gvalid(h3);
        if (__ballot(allv) != ~0ull) {
            // fallback: round-7 poll (each sample fully drained in-asm; no
            // abandoned in-flight loads at exit)
            unsigned it = 0;
            for (;;) {
                asm volatile(
                    "global_load_dwordx4 %0, %4, off sc0 sc1\n\t"
                    "global_load_dwordx4 %1, %4, off offset:64 sc0 sc1\n\t"
                    "global_load_dwordx4 %2, %4, off offset:128 sc0 sc1\n\t"
                    "global_load_dwordx4 %3, %4, off offset:192 sc0 sc1\n\t"
                    "s_waitcnt vmcnt(0)"
                    : "=&v"(h0), "=&v"(h1), "=&v"(h2), "=&v"(h3)
                    : "v"(haddr) : "memory");
                bool ok = gvalid(h0) && gvalid(h1) && gvalid(h2) && gvalid(h3);
                if (__ballot(ok) == ~0ull || dead) break;
                if (++it > 2000000u) { dead = true; break; }
            }
        }

        float x_next = x[(size_t)(t + 1 < T_STEPS ? t + 1 : t) * BATCH + g * 16 + row_e];

        // ---- 32 MFMAs: 4 gates x 2 col-halves x 4 k-sub-slices ----
        f32x4 acc[4][2];
        #pragma unroll
        for (int gt = 0; gt < 4; ++gt) {
            acc[gt][0] = (f32x4){0.f, 0.f, 0.f, 0.f};
            acc[gt][1] = (f32x4){0.f, 0.f, 0.f, 0.f};
        }
        #define KSTEP(ksl, hx) {                                                      \
            half8 af = __builtin_bit_cast(half8, hx);                                 \
            _Pragma("unroll")                                                         \
            for (int gt = 0; gt < 4; ++gt) {                                          \
                acc[gt][0] = __builtin_amdgcn_mfma_f32_16x16x32_f16(af, bf[gt][0][ksl], acc[gt][0], 0, 0, 0); \
                acc[gt][1] = __builtin_amdgcn_mfma_f32_16x16x32_f16(af, bf[gt][1][ksl], acc[gt][1], 0, 0, 0); \
            } }
        KSTEP(0, h0) KSTEP(1, h1) KSTEP(2, h2) KSTEP(3, h3)
        #undef KSTEP

        const int tb = t & 1;
        #pragma unroll
        for (int gt = 0; gt < 4; ++gt) {
            #pragma unroll
            for (int r = 0; r < 4; ++r) {
                lds_part[tb][wave][gt][quad * 4 + r][ln16]      = acc[gt][0][r];
                lds_part[tb][wave][gt][quad * 4 + r][16 + ln16] = acc[gt][1][r];
            }
        }
        // raw barrier: LDS handoff needs lgkmcnt only (x_next is private)
        asm volatile("s_waitcnt lgkmcnt(0)\n\ts_barrier" ::: "memory");

        // ---- reset consumed slot s_rst: one dwordx4 per 4 lanes ----
        if ((lane & 3) == 0) {
            unsigned long long radr = (unsigned long long)(
                (char*)hbuf
                + ((size_t)s_rst * (BATCH * HID)
                   + (size_t)(g * 16 + row_e) * HID + j * 32 + cp) * 2);
            asm volatile("global_store_dwordx4 %0, %1, off sc0 sc1"
                         : : "v"(radr), "v"(sent4) : "memory");
        }

        // ---- EARLY PROBE for next step's slot: flight overlaps epilogue+store ----
        {
            const unsigned long long naddr = lane_base + (unsigned long long)s_out * slot_stride;
            PROBE(naddr);
        }

        // ---- epilogue ----
        const float xin = x_cur;
        float sA[4] = {0.f, 0.f, 0.f, 0.f};
        float sB[4] = {0.f, 0.f, 0.f, 0.f};
        #pragma unroll
        for (int w = 0; w < 4; ++w) {
            #pragma unroll
            for (int gt = 0; gt < 4; ++gt) {
                float2 v = *(const float2*)&lds_part[tb][w][gt][row_e][cp];
                sA[gt] += v.x;
                sB[gt] += v.y;
            }
        }
        float hv0, hv1;
        {
            float gi = sA[0] + xin * wxA[0] + bsA[0];
            float gf = sA[1] + xin * wxA[1] + bsA[1];
            float gg = sA[2] + xin * wxA[2] + bsA[2];
            float go = sA[3] + xin * wxA[3] + bsA[3];
            float iv = sigmoid_f(gi), fv = sigmoid_f(gf), gv = tanh_f(gg), ov = sigmoid_f(go);
            c0 = fv * c0 + iv * gv;
            hv0 = ov * tanh_f(c0);
        }
        {
            float gi = sB[0] + xin * wxB[0] + bsB[0];
            float gf = sB[1] + xin * wxB[1] + bsB[1];
            float gg = sB[2] + xin * wxB[2] + bsB[2];
            float go = sB[3] + xin * wxB[3] + bsB[3];
            float iv = sigmoid_f(gi), fv = sigmoid_f(gf), gv = tanh_f(gg), ov = sigmoid_f(go);
            c1 = fv * c1 + iv * gv;
            hv1 = ov * tanh_f(c1);
        }
        hl0 = hv0; hl1 = hv1;

        // ---- per-lane dword h(t+1) store (round-7 proven publish path) ----
        {
            _Float16 p0 = (_Float16)hv0, p1 = (_Float16)hv1;
            unsigned hbits = ((unsigned)__builtin_bit_cast(unsigned short, p1) << 16)
                           |  (unsigned)__builtin_bit_cast(unsigned short, p0);
            unsigned long long sadr = (unsigned long long)(
                (char*)hbuf
                + ((size_t)s_out * (BATCH * HID)
                   + (size_t)(g * 16 + row_e) * HID + j * 32 + cp) * 2);
            asm volatile("global_store_dword %0, %1, off sc0 sc1"
                         : : "v"(sadr), "v"(hbits) : "memory");
        }
        // no end-of-step drain: next loop-top WAITQ() (vmcnt(0)) retires the
        // store + reset acks together with the probe flight.

        x_cur = x_next;
        s_rst = s_in;
        s_in  = s_out;
        s_out = (s_out + 1 == RING) ? 0 : s_out + 1;
    }
    WAITQ();  // land the final (unused) probe before its regs are reused

    // ---- partial output: sum over this block's 32 h-cols per row ----
    float p = hl0 * Wlin[j * 32 + cp] + hl1 * Wlin[j * 32 + cp + 1];
    #pragma unroll
    for (int off = 8; off; off >>= 1) p += __shfl_down(p, off, 16);
    if ((tid & 15) == 0) partial[(size_t)j * BATCH + g * 16 + row_e] = p;
}

__global__ void lstm_finalize(const float* __restrict__ partial,
                              const float* __restrict__ blin,
                              float* __restrict__ out)
{
    int b = threadIdx.x;
    float s = blin[0];
    #pragma unroll
    for (int jj = 0; jj < NG; ++jj) s += partial[(size_t)jj * BATCH + b];
    out[b] = s;
}

extern "C" void kernel_launch(void* const* d_in, const int* in_sizes, int n_in,
                              void* d_out, int out_size, void* d_ws, size_t ws_size,
                              hipStream_t stream) {
    const float* x    = (const float*)d_in[0];
    const float* Wih  = (const float*)d_in[1];
    const float* Whh  = (const float*)d_in[2];
    const float* bih  = (const float*)d_in[3];
    const float* bhh  = (const float*)d_in[4];
    const float* Wlin = (const float*)d_in[5];
    const float* blin = (const float*)d_in[6];

    char* ws = (char*)d_ws;
    _Float16* hbuf    = (_Float16*)ws;                   // RING * 256KB = 1.5 MB
    float*    partial = (float*)(ws + (2 << 20));        // 16 KB

    const size_t slot_bytes = (size_t)BATCH * HID * sizeof(_Float16);  // 256 KB
    // slot 0 = zeros (h(-1)); slots 1..5 = sentinel bytes
    hipMemsetAsync(hbuf, 0, slot_bytes, stream);
    hipMemsetAsync((char*)hbuf + slot_bytes, 0x3C, (RING - 1) * slot_bytes, stream);

    lstm_persistent<<<dim3(256), dim3(256), 0, stream>>>(
        x, Wih, Whh, bih, bhh, Wlin, hbuf, partial);
    lstm_finalize<<<dim3(1), dim3(256), 0, stream>>>(partial, blin, (float*)d_out);
}

// Round 12
// 5144.735 us; speedup vs baseline: 1.3929x; 1.3929x over previous
//
#include <hip/hip_runtime.h>

#define T_STEPS 2048
#define BATCH   256
#define HID     512
#define NG      16   // gate-slice blocks per batch group (h-cols 512/NG = 32 each)
#define NB      16   // batch groups (rows 256/NB = 16 each)
#define RING    6    // h ring slots (sentinel dataflow protocol)
#define SENT    0x3C3C3C3C  // fp16 pair (1.0586,1.0586) — unreachable: |h|<=1.0

typedef _Float16 half8 __attribute__((ext_vector_type(8)));
typedef float f32x4 __attribute__((ext_vector_type(4)));
typedef int int4v __attribute__((ext_vector_type(4)));

__device__ __forceinline__ float sigmoid_f(float v) {
    return 1.f / (1.f + __expf(-v));
}
__device__ __forceinline__ float tanh_f(float v) {
    float a = fabsf(v);
    float e = __expf(2.f * a);
    float r = 1.f - 2.f / (e + 1.f);
    return copysignf(r, v);
}
__device__ __forceinline__ bool gvalid(int4v p) {
    return p[0] != (int)SENT && p[1] != (int)SENT &&
           p[2] != (int)SENT && p[3] != (int)SENT;
}

// grid = 256 blocks (g = blockIdx&15 batch group, j = blockIdx>>4 gate slice)
// block = 256 threads = 4 waves, K-split (wave w owns k in [128w,128w+128)).
//
// CONSOLIDATED BEST (r12): exact round-7 protocol (4.38 ms verified) +
//   pad-36 LDS        (r9-verified: conflicts 2.01e8 -> 6.7e7)
//   dwordx4 reset     (r9-verified: 4x fewer reset requests, fire-and-forget)
//   lgkmcnt-only barrier (doesn't drain the x_next load)
// Detect-timing "optimizations" (vmcnt(4) pipelining r9, early probe r11)
// are all REGRESSIONS — the simple RTT-paced sample is the floor.
//
// Sentinel-dataflow sync: 6-slot h ring; producers store h (sc0|sc1, MALL-
// coherent); consumers poll their own A-fragment granules until != SENT —
// the poll IS the load. Consumed slot (t-1)%6 reset to SENT after the
// mid-step barrier (poll success at t proves all peers finished step t-1,
// so nobody still reads it; 4-step slack covers reset visibility).
__global__ __launch_bounds__(256, 1) void lstm_persistent(
    const float* __restrict__ x,     // (T,B)
    const float* __restrict__ Wih,   // (4H,1)
    const float* __restrict__ Whh,   // (4H,H)
    const float* __restrict__ bih,   // (4H)
    const float* __restrict__ bhh,   // (4H)
    const float* __restrict__ Wlin,  // (1,H)
    _Float16* __restrict__ hbuf,     // [RING][B][H] fp16
    float* __restrict__ partial)     // [NG][B]
{
    const int tid  = threadIdx.x;
    const int g    = blockIdx.x & 15;   // batch group
    const int j    = blockIdx.x >> 4;   // gate slice
    const int wave = tid >> 6;          // k-slice owner
    const int lane = tid & 63;
    const int quad = lane >> 4;
    const int ln16 = lane & 15;

    // pad 36: write bank = (16q + 4r + col) % 32 -> exact 2-way (free).
    // Double-buffered (t&1) -> single barrier per step.
    __shared__ float lds_part[2][4][4][16][36];

    // ---- stationary weights: fp16 MFMA B-fragments in registers ----
    // bf[gate][colhalf][ksl]: B[k][n] = Whh[gate*512 + j*32 + colhalf*16 + ln16][k],
    // k = (wave*4 + ksl)*32 + quad*8 + e
    half8 bf[4][2][4];
    #pragma unroll
    for (int gt = 0; gt < 4; ++gt) {
        #pragma unroll
        for (int ch = 0; ch < 2; ++ch) {
            const float* wr = Whh + (size_t)(gt * 512 + j * 32 + ch * 16 + ln16) * HID;
            #pragma unroll
            for (int ksl = 0; ksl < 4; ++ksl) {
                int k0 = (wave * 4 + ksl) * 32 + quad * 8;
                half8 v;
                #pragma unroll
                for (int e = 0; e < 8; ++e) v[e] = (_Float16)wr[k0 + e];
                bf[gt][ch][ksl] = v;
            }
        }
    }

    const int row_e = tid >> 4;          // epilogue row 0..15
    const int cp    = (tid & 15) * 2;    // epilogue col pair 0,2,..,30

    // per-thread epilogue constants in registers
    float wxA[4], wxB[4], bsA[4], bsB[4];
    #pragma unroll
    for (int gt = 0; gt < 4; ++gt) {
        int r0 = gt * 512 + j * 32 + cp;
        wxA[gt] = Wih[r0];
        wxB[gt] = Wih[r0 + 1];
        bsA[gt] = bih[r0] + bhh[r0];
        bsB[gt] = bih[r0 + 1] + bhh[r0 + 1];
    }

    float c0 = 0.f, c1 = 0.f;            // cell state (fp32, register-resident)
    float hl0 = 0.f, hl1 = 0.f;          // last h values (fp32)
    bool  dead = false;                  // sticky bailout

    float x_cur = x[(size_t)g * 16 + row_e];   // x for t=0

    const int4v sent4 = {(int)SENT, (int)SENT, (int)SENT, (int)SENT};
    int s_in = 0, s_out = 1, s_rst = 5;

    // per-lane A-fragment base (slot 0); slot stride = 256 KB
    const unsigned long long lane_base = (unsigned long long)(
        (const char*)hbuf + ((size_t)(g * 16 + ln16) * HID) * 2
        + wave * 256 + quad * 16);
    const unsigned long long slot_stride = (unsigned long long)BATCH * HID * 2;

    for (int t = 0; t < T_STEPS; ++t) {
        // ---- sentinel poll on own A-fragment granules (the poll IS the load) ----
        const unsigned long long haddr =
            lane_base + (unsigned long long)s_in * slot_stride;
        int4v h0, h1, h2, h3;
        {
            unsigned it = 0;
            for (;;) {
                asm volatile(
                    "global_load_dwordx4 %0, %4, off sc0 sc1\n\t"
                    "global_load_dwordx4 %1, %4, off offset:64 sc0 sc1\n\t"
                    "global_load_dwordx4 %2, %4, off offset:128 sc0 sc1\n\t"
                    "global_load_dwordx4 %3, %4, off offset:192 sc0 sc1\n\t"
                    "s_waitcnt vmcnt(0)"
                    : "=&v"(h0), "=&v"(h1), "=&v"(h2), "=&v"(h3)
                    : "v"(haddr) : "memory");
                bool ok = gvalid(h0) && gvalid(h1) && gvalid(h2) && gvalid(h3);
                if (__ballot(ok) == ~0ull || dead) break;
                if (++it > 2000000u) { dead = true; break; }
            }
        }

        // prefetch x for next step (overlaps MFMA + epilogue)
        float x_next = x[(size_t)(t + 1 < T_STEPS ? t + 1 : t) * BATCH + g * 16 + row_e];

        // ---- 32 MFMAs: 4 gates x 2 col-halves x 4 k-sub-slices (partials) ----
        f32x4 acc[4][2];
        #pragma unroll
        for (int gt = 0; gt < 4; ++gt) {
            acc[gt][0] = (f32x4){0.f, 0.f, 0.f, 0.f};
            acc[gt][1] = (f32x4){0.f, 0.f, 0.f, 0.f};
        }
        #define KSTEP(ksl, hx) {                                                      \
            half8 af = __builtin_bit_cast(half8, hx);                                 \
            _Pragma("unroll")                                                         \
            for (int gt = 0; gt < 4; ++gt) {                                          \
                acc[gt][0] = __builtin_amdgcn_mfma_f32_16x16x32_f16(af, bf[gt][0][ksl], acc[gt][0], 0, 0, 0); \
                acc[gt][1] = __builtin_amdgcn_mfma_f32_16x16x32_f16(af, bf[gt][1][ksl], acc[gt][1], 0, 0, 0); \
            } }
        KSTEP(0, h0) KSTEP(1, h1) KSTEP(2, h2) KSTEP(3, h3)
        #undef KSTEP

        // C layout: col = ln16, row = quad*4 + r  -> per-wave partials to LDS
        const int tb = t & 1;
        #pragma unroll
        for (int gt = 0; gt < 4; ++gt) {
            #pragma unroll
            for (int r = 0; r < 4; ++r) {
                lds_part[tb][wave][gt][quad * 4 + r][ln16]      = acc[gt][0][r];
                lds_part[tb][wave][gt][quad * 4 + r][16 + ln16] = acc[gt][1][r];
            }
        }
        // raw barrier: LDS handoff needs lgkmcnt only (x_next load stays in flight)
        asm volatile("s_waitcnt lgkmcnt(0)\n\ts_barrier" ::: "memory");

        // ---- reset consumed slot s_rst: one dwordx4 per 4 threads ----
        if ((lane & 3) == 0) {
            unsigned long long radr = (unsigned long long)(
                (char*)hbuf
                + ((size_t)s_rst * (BATCH * HID)
                   + (size_t)(g * 16 + row_e) * HID + j * 32 + cp) * 2);
            asm volatile("global_store_dwordx4 %0, %1, off sc0 sc1"
                         : : "v"(radr), "v"(sent4) : "memory");
        }

        // ---- epilogue: reduce 4 wave-partials, activations, c/h update ----
        const float xin = x_cur;
        float sA[4] = {0.f, 0.f, 0.f, 0.f};
        float sB[4] = {0.f, 0.f, 0.f, 0.f};
        #pragma unroll
        for (int w = 0; w < 4; ++w) {
            #pragma unroll
            for (int gt = 0; gt < 4; ++gt) {
                float2 v = *(const float2*)&lds_part[tb][w][gt][row_e][cp];
                sA[gt] += v.x;
                sB[gt] += v.y;
            }
        }
        float hv0, hv1;
        {
            float gi = sA[0] + xin * wxA[0] + bsA[0];
            float gf = sA[1] + xin * wxA[1] + bsA[1];
            float gg = sA[2] + xin * wxA[2] + bsA[2];
            float go = sA[3] + xin * wxA[3] + bsA[3];
            float iv = sigmoid_f(gi), fv = sigmoid_f(gf), gv = tanh_f(gg), ov = sigmoid_f(go);
            c0 = fv * c0 + iv * gv;
            hv0 = ov * tanh_f(c0);
        }
        {
            float gi = sB[0] + xin * wxB[0] + bsB[0];
            float gf = sB[1] + xin * wxB[1] + bsB[1];
            float gg = sB[2] + xin * wxB[2] + bsB[2];
            float go = sB[3] + xin * wxB[3] + bsB[3];
            float iv = sigmoid_f(gi), fv = sigmoid_f(gf), gv = tanh_f(gg), ov = sigmoid_f(go);
            c1 = fv * c1 + iv * gv;
            hv1 = ov * tanh_f(c1);
        }
        hl0 = hv0; hl1 = hv1;

        // ---- per-lane dword h(t+1) store: the data store IS the publish ----
        {
            _Float16 p0 = (_Float16)hv0, p1 = (_Float16)hv1;
            unsigned hbits = ((unsigned)__builtin_bit_cast(unsigned short, p1) << 16)
                           |  (unsigned)__builtin_bit_cast(unsigned short, p0);
            unsigned long long sadr = (unsigned long long)(
                (char*)hbuf
                + ((size_t)s_out * (BATCH * HID)
                   + (size_t)(g * 16 + row_e) * HID + j * 32 + cp) * 2);
            asm volatile("global_store_dword %0, %1, off sc0 sc1"
                         : : "v"(sadr), "v"(hbits) : "memory");
        }
        // no end-of-step drain: next poll's vmcnt(0) retires store/reset acks.

        x_cur = x_next;
        s_rst = s_in;
        s_in  = s_out;
        s_out = (s_out + 1 == RING) ? 0 : s_out + 1;
    }

    // ---- partial output: sum over this block's 32 h-cols per row ----
    float p = hl0 * Wlin[j * 32 + cp] + hl1 * Wlin[j * 32 + cp + 1];
    #pragma unroll
    for (int off = 8; off; off >>= 1) p += __shfl_down(p, off, 16);
    if ((tid & 15) == 0) partial[(size_t)j * BATCH + g * 16 + row_e] = p;
}

__global__ void lstm_finalize(const float* __restrict__ partial,
                              const float* __restrict__ blin,
                              float* __restrict__ out)
{
    int b = threadIdx.x;
    float s = blin[0];
    #pragma unroll
    for (int jj = 0; jj < NG; ++jj) s += partial[(size_t)jj * BATCH + b];
    out[b] = s;
}

extern "C" void kernel_launch(void* const* d_in, const int* in_sizes, int n_in,
                              void* d_out, int out_size, void* d_ws, size_t ws_size,
                              hipStream_t stream) {
    const float* x    = (const float*)d_in[0];
    const float* Wih  = (const float*)d_in[1];
    const float* Whh  = (const float*)d_in[2];
    const float* bih  = (const float*)d_in[3];
    const float* bhh  = (const float*)d_in[4];
    const float* Wlin = (const float*)d_in[5];
    const float* blin = (const float*)d_in[6];

    char* ws = (char*)d_ws;
    _Float16* hbuf    = (_Float16*)ws;                   // RING * 256KB = 1.5 MB
    float*    partial = (float*)(ws + (2 << 20));        // 16 KB

    const size_t slot_bytes = (size_t)BATCH * HID * sizeof(_Float16);  // 256 KB
    // slot 0 = zeros (h(-1)); slots 1..5 = sentinel bytes
    hipMemsetAsync(hbuf, 0, slot_bytes, stream);
    hipMemsetAsync((char*)hbuf + slot_bytes, 0x3C, (RING - 1) * slot_bytes, stream);

    lstm_persistent<<<dim3(256), dim3(256), 0, stream>>>(
        x, Wih, Whh, bih, bhh, Wlin, hbuf, partial);
    lstm_finalize<<<dim3(1), dim3(256), 0, stream>>>(partial, blin, (float*)d_out);
}